// Round 5
// baseline (538.185 us; speedup 1.0000x reference)
//
#include <hip/hip_runtime.h>

// Izhikevich scan, R6: two-pass checkpoint/replay.
// R3/R4/R5 post-mortem: izh time invariant ~243-255us across four store
// choreographies. Fill counters show ~3.2 B/cyc per STORING WAVE at 6.3 TB/s
// aggregate (820 waves); our structure pins 1 storing wave/CU (256 chains-
// groups, sequential recurrence) => 256 x 3 B/cyc = 1.7 TB/s. Store drain is
// per-wave-throughput-bound; only more storing waves (TLP) fixes it.
//
// Pass 1 (256 blocks x 1 wave): full recurrence, NO output stores; LDS-staged
//   input (global_load_lds chunks, double-buffered); dump (v,u) checkpoints
//   every CHUNK=100 steps to d_ws (20 x 16384 x 2 floats = 2.6 MB).
// Pass 2 (20 x 256 = 5120 blocks x 1 wave): each wave loads its checkpoint,
//   replays its 100-step segment with IDENTICAL op order (bit-exact), writes
//   s/v/u. 16+ independent storing waves/CU => store drain scales to HBM BW.
//
// NUMERICS: exact numpy op order, fp contract off; pass-2 replay starts from
// pass-1 state => bit-identical to a continuous scan.

#define NSTEPS 2000
#define NNEUR  512
#define BATCH  32
#define INPLANE 1024000u                       // NSTEPS*NNEUR per batch
#define PLANE  32768000u                       // BATCH*NSTEPS*NNEUR per out plane
#define CHUNK  100                             // steps per chunk == per segment
#define NCHUNK (NSTEPS / CHUNK)                // 20
#define NG     (CHUNK / 4)                     // 25 staging groups of 4 steps
#define NCHAIN 16384u                          // BATCH*NNEUR
#define WIN    10                              // inner window (steps)

typedef const __attribute__((address_space(1))) unsigned GPtr;
typedef __attribute__((address_space(3))) unsigned LPtr;

__device__ __forceinline__ void izh_step(float i_t, float& v, float& u, float& s) {
#pragma clang fp contract(off)
    float t1 = 0.04f * v;
    t1 = t1 * v;
    float t2 = 5.0f * v;
    float acc = t1 + t2;
    acc = acc + 140.0f;
    acc = acc - u;
    acc = acc + i_t;
    float dv = acc * 0.5f;
    float t4 = 0.2f * v;
    t4 = t4 - u;
    t4 = 0.02f * t4;
    float du = t4 * 0.5f;
    v = v + dv;
    u = u + du;
    bool sp = (v >= 30.0f);
    s = sp ? 1.0f : 0.0f;
    v = sp ? -65.0f : v;
    u = sp ? (u + 8.0f) : u;
}

// ---------------- pass 1: recurrence only, checkpoint every CHUNK ----------
__global__ __launch_bounds__(64, 1) void izh_pass1(const float* __restrict__ in,
                                                   float* __restrict__ ckV,
                                                   float* __restrict__ ckU) {
    __shared__ float lin[2][CHUNK * 64];       // 51.2 KB input staging

    const int lane = threadIdx.x;
    const unsigned gid = blockIdx.x * 64u + (unsigned)lane;
    const unsigned b   = gid >> 9;
    const unsigned n0  = (unsigned)((blockIdx.x * 64) & (NNEUR - 1));
    // lane L stages step (L>>4), 16B at neurons n0+(L&15)*4 (LDS step-major)
    const float* gsrc = in + (size_t)b * INPLANE + (size_t)(lane >> 4) * NNEUR
                           + n0 + (size_t)(lane & 15) * 4;
#pragma unroll
    for (int g = 0; g < NG; ++g)
        __builtin_amdgcn_global_load_lds((GPtr*)(gsrc + (size_t)(4 * g) * NNEUR),
                                         (LPtr*)&lin[0][g * 256], 16, 0, 0);

    float v = -65.0f, u = -13.0f;              // C, B*C exactly
    for (int c = 0; c < NCHUNK; ++c) {
        asm volatile("s_waitcnt vmcnt(0)" ::: "memory");   // chunk c resident
        if (c + 1 < NCHUNK) {                  // stage chunk c+1 (other buffer)
            const float* gs = gsrc + (size_t)(c + 1) * CHUNK * NNEUR;
            float* lb = &lin[(c + 1) & 1][0];
#pragma unroll
            for (int g = 0; g < NG; ++g)
                __builtin_amdgcn_global_load_lds((GPtr*)(gs + (size_t)(4 * g) * NNEUR),
                                                 (LPtr*)(lb + g * 256), 16, 0, 0);
        }
        // checkpoint = state entering chunk c (after 100c steps); copy to
        // temps so the live v,u regs aren't store-pinned
        {
            float vc = v, uc = u;
            ckV[(unsigned)c * NCHAIN + gid] = vc;
            ckU[(unsigned)c * NCHAIN + gid] = uc;
        }
        const float* lbuf = &lin[c & 1][0];
        float ra[WIN], rb[WIN];
#pragma unroll
        for (int j = 0; j < WIN; ++j) ra[j] = lbuf[j * 64 + lane];
        for (int w = 0; w < CHUNK / WIN; w += 2) {
#pragma unroll
            for (int j = 0; j < WIN; ++j) rb[j] = lbuf[((w + 1) * WIN + j) * 64 + lane];
#pragma unroll
            for (int j = 0; j < WIN; ++j) { float s; izh_step(ra[j], v, u, s); }
            if (w + 2 < CHUNK / WIN) {
#pragma unroll
                for (int j = 0; j < WIN; ++j) ra[j] = lbuf[((w + 2) * WIN + j) * 64 + lane];
            }
#pragma unroll
            for (int j = 0; j < WIN; ++j) { float s; izh_step(rb[j], v, u, s); }
        }
    }
}

// ---------------- pass 2: segment replay + all output stores ---------------
__global__ __launch_bounds__(64, 4) void izh_pass2(const float* __restrict__ in,
                                                   float* __restrict__ out,
                                                   const float* __restrict__ ckV,
                                                   const float* __restrict__ ckU) {
    const int lane = threadIdx.x;
    const unsigned sp  = (unsigned)blockIdx.x & 255u;    // chain-group
    const unsigned seg = (unsigned)blockIdx.x >> 8;      // time segment 0..19
    const unsigned gid = sp * 64u + (unsigned)lane;
    const unsigned b   = gid >> 9;
    const unsigned n   = gid & (NNEUR - 1);

    float v = ckV[seg * NCHAIN + gid];
    float u = ckU[seg * NCHAIN + gid];

    const size_t base = (size_t)b * INPLANE + (size_t)seg * CHUNK * NNEUR + n;
    const float* ip = in + base;
    float* oS = out;
    float* oV = out + (size_t)PLANE;
    float* oU = out + 2 * (size_t)PLANE;
    size_t off = base;

    float ra[WIN], rb[WIN];
#pragma unroll
    for (int j = 0; j < WIN; ++j) ra[j] = ip[(size_t)j * NNEUR];

    for (int w = 0; w < CHUNK / WIN; w += 2) {
        // prefetch window w+1 while computing window w
#pragma unroll
        for (int j = 0; j < WIN; ++j) rb[j] = ip[(size_t)((w + 1) * WIN + j) * NNEUR];
        {
            float sB[WIN], vB[WIN], uB[WIN];
#pragma unroll
            for (int j = 0; j < WIN; ++j) { izh_step(ra[j], v, u, sB[j]); vB[j] = v; uB[j] = u; }
#pragma unroll
            for (int j = 0; j < WIN; ++j) {
                oS[off + (size_t)j * NNEUR] = sB[j];
                oV[off + (size_t)j * NNEUR] = vB[j];
                oU[off + (size_t)j * NNEUR] = uB[j];
            }
            off += (size_t)WIN * NNEUR;
        }
        if (w + 2 < CHUNK / WIN) {
#pragma unroll
            for (int j = 0; j < WIN; ++j) ra[j] = ip[(size_t)((w + 2) * WIN + j) * NNEUR];
        }
        {
            float sB[WIN], vB[WIN], uB[WIN];
#pragma unroll
            for (int j = 0; j < WIN; ++j) { izh_step(rb[j], v, u, sB[j]); vB[j] = v; uB[j] = u; }
#pragma unroll
            for (int j = 0; j < WIN; ++j) {
                oS[off + (size_t)j * NNEUR] = sB[j];
                oV[off + (size_t)j * NNEUR] = vB[j];
                oU[off + (size_t)j * NNEUR] = uB[j];
            }
            off += (size_t)WIN * NNEUR;
        }
    }
}

extern "C" void kernel_launch(void* const* d_in, const int* in_sizes, int n_in,
                              void* d_out, int out_size, void* d_ws, size_t ws_size,
                              hipStream_t stream) {
    const float* in = (const float*)d_in[0];
    float* out = (float*)d_out;
    float* ckV = (float*)d_ws;                         // 20*16384 floats
    float* ckU = ckV + (size_t)NCHUNK * NCHAIN;        // +1.31 MB (2.62 MB total)
    izh_pass1<<<256, 64, 0, stream>>>(in, ckV, ckU);
    izh_pass2<<<NCHUNK * 256, 64, 0, stream>>>(in, out, ckV, ckU);
}